// Round 2
// 130.422 us; speedup vs baseline: 1.0570x; 1.0570x over previous
//
#include <hip/hip_runtime.h>

#define NN 2048
#define DD 64
#define C1 0.36067376f  // 2/sqrt(D) * log2(e)
#define C1H 0.18033688f // C1/2

typedef _Float16 h8 __attribute__((ext_vector_type(8)));
typedef _Float16 h4 __attribute__((ext_vector_type(4)));
typedef float f32x16 __attribute__((ext_vector_type(16)));

union H8U4 { h8 v; unsigned u[4]; };

// ---- prep: frag-major swizzles so the main loop is pure coalesced loads ----
// Ks[bh][jj][c][lh][ln]{8}  = K[32jj+ln][16c+8lh+0..7]          (A-frag order)
// Vs[bh][jj][o][c][lh][ln]{8}= V[32jj+16c+8lh+j][32o+ln]        (V^T A-frag order)
// hk[bh][n] = C1H*||k_n||^2
__global__ __launch_bounds__(64) void prep(const float* __restrict__ k,
                                           const float* __restrict__ v,
                                           _Float16* __restrict__ Ks,
                                           _Float16* __restrict__ Vs,
                                           float* __restrict__ hk) {
    __shared__ _Float16 T[32][72];
    const int jj = blockIdx.x, bh = blockIdx.y, lane = threadIdx.x;
    const int ln = lane & 31, lh = lane >> 5;
    const size_t ibase = (size_t)bh * NN * DD + (size_t)jj * 32 * DD;

    { // K frags + row sumsq (lh halves cover complementary d-ranges)
        const float* kr = k + ibase + (size_t)ln * DD;
        float s = 0.f;
#pragma unroll
        for (int c = 0; c < 4; ++c) {
            float4 a = *(const float4*)&kr[16 * c + 8 * lh];
            float4 b = *(const float4*)&kr[16 * c + 8 * lh + 4];
            h8 o = {(_Float16)a.x, (_Float16)a.y, (_Float16)a.z, (_Float16)a.w,
                    (_Float16)b.x, (_Float16)b.y, (_Float16)b.z, (_Float16)b.w};
            *(h8*)&Ks[((size_t)bh * 16384 + jj * 256 + c * 64 + lh * 32 + ln) * 8] = o;
            s += a.x*a.x + a.y*a.y + a.z*a.z + a.w*a.w
               + b.x*b.x + b.y*b.y + b.z*b.z + b.w*b.w;
        }
        s += __shfl_xor(s, 32);
        if (lh == 0) hk[bh * NN + jj * 32 + ln] = s * C1H;
    }

    // V tile -> LDS f16 -> transposed frag-major store
#pragma unroll
    for (int t = 0; t < 8; ++t) {
        int f = lane + 64 * t;            // 512 float4 groups = 32 rows x 16
        int row = f >> 4, c4 = (f & 15) * 4;
        float4 a = *(const float4*)&v[ibase + (size_t)row * DD + c4];
        h4 hv = {(_Float16)a.x, (_Float16)a.y, (_Float16)a.z, (_Float16)a.w};
        *(h4*)&T[row][c4] = hv;
    }
    __syncthreads();
#pragma unroll
    for (int oc = 0; oc < 4; ++oc) {
        int o = oc >> 1, c = oc & 1;
        h8 r;
#pragma unroll
        for (int jx = 0; jx < 8; ++jx) r[jx] = T[16 * c + 8 * lh + jx][32 * o + ln];
        *(h8*)&Vs[((size_t)bh * 16384 + jj * 256 + o * 128 + c * 64 + lh * 32 + ln) * 8] = r;
    }
}

// ---- main: online-softmax flash RBF, key-split across 2 waves per q-tile ----
// Block = 2 waves on the SAME 32-row q-tile; wave0 keys [0,ceil(T/2)), wave1 the
// rest incl. diagonal. Partials (m,l,O) merge via flash combine through LDS.
__global__ __launch_bounds__(128, 2) void rbf_attn(
    const float* __restrict__ q, const _Float16* __restrict__ Ks,
    const _Float16* __restrict__ Vs, const float* __restrict__ hk,
    float* __restrict__ out)
{
    __shared__ float sm[64][34];         // wave1: O (32 f32/lane) + l + m
    const int tid = threadIdx.x;
    const int bh = blockIdx.x;
    const int qt = 63 - (int)blockIdx.y; // q-tile (32 rows); LPT: heavy first
    const int wv = tid >> 6, lane = tid & 63;
    const int ln = lane & 31, lh = lane >> 5;
    const int qrow = qt * 32 + ln;
    const size_t fbase = (size_t)bh * NN * DD;

    // Q B-frags straight from global f32 (per-lane 16B-contiguous, L2-hot)
    h8 qf[4];
    {
        const float* qr = q + fbase + (size_t)qrow * DD;
#pragma unroll
        for (int c = 0; c < 4; ++c) {
            float4 a = *(const float4*)&qr[16 * c + 8 * lh];
            float4 b = *(const float4*)&qr[16 * c + 8 * lh + 4];
            qf[c] = h8{(_Float16)a.x, (_Float16)a.y, (_Float16)a.z, (_Float16)a.w,
                       (_Float16)b.x, (_Float16)b.y, (_Float16)b.z, (_Float16)b.w};
        }
    }

    const _Float16* Ksb = Ks + (size_t)bh * 131072;
    const _Float16* Vsb = Vs + (size_t)bh * 131072;
    const float4* hk4 = (const float4*)(hk + bh * NN);
    const int klq = (lh * 32 + ln) * 8;  // element offset of this lane's frag

    f32x16 O0, O1;
#pragma unroll
    for (int r = 0; r < 16; ++r) { O0[r] = 0.f; O1[r] = 0.f; }
    float lsum = 0.f, mrun = -INFINITY;

    const int T = qt + 1;                // key tiles for this q-tile
    const int half = (T + 1) >> 1;       // wave0 gets ceil (wave1 pays diag mask)
    const int j0 = wv ? half : 0;
    const int j1 = wv ? T : half;

    auto loadT = [&](int jj, h8 (&kf)[4], h8 (&vf)[4], float4 (&hr)[4]) {
        const _Float16* kp = Ksb + (size_t)jj * 2048 + klq;
        const _Float16* vp = Vsb + (size_t)jj * 2048 + klq;
#pragma unroll
        for (int c = 0; c < 4; ++c) kf[c] = *(const h8*)(kp + c * 512);
#pragma unroll
        for (int oc = 0; oc < 4; ++oc)
            vf[oc] = *(const h8*)(vp + (oc >> 1) * 1024 + (oc & 1) * 512);
#pragma unroll
        for (int g = 0; g < 4; ++g) hr[g] = hk4[jj * 8 + g * 2 + lh];
    };

    auto comp = [&](int jj, h8 (&kf)[4], h8 (&vf)[4], float4 (&hr)[4]) {
        f32x16 S;
#pragma unroll
        for (int r = 0; r < 16; ++r) S[r] = 0.f;
#pragma unroll
        for (int c = 0; c < 4; ++c)
            S = __builtin_amdgcn_mfma_f32_32x32x16_f16(kf[c], qf[c], S, 0, 0, 0);

        const bool diag = (jj == qt);
        float x[16];
#pragma unroll
        for (int r = 0; r < 16; ++r) {
            const float* hf = (const float*)&hr[r >> 2];
            float xv = fmaf(S[r], C1, -hf[r & 3]);
            if (diag) {
                int keyloc = (r & 3) + 8 * (r >> 2) + 4 * lh;
                if (keyloc > ln) xv = -INFINITY;
            }
            x[r] = xv;
        }
        float mt = x[0];
#pragma unroll
        for (int r = 1; r < 16; ++r) mt = fmaxf(mt, x[r]);
        mt = fmaxf(mt, __shfl_xor(mt, 32));
        float mnew = fmaxf(mrun, mt);
        float alpha = __builtin_amdgcn_exp2f(mrun - mnew);
        mrun = mnew;
        float p[16], ps = 0.f;
#pragma unroll
        for (int r = 0; r < 16; ++r) {
            p[r] = __builtin_amdgcn_exp2f(x[r] - mnew);
            ps += p[r];
        }
        lsum = fmaf(lsum, alpha, ps);
#pragma unroll
        for (int r = 0; r < 16; ++r) { O0[r] *= alpha; O1[r] *= alpha; }

        unsigned pk[8];
#pragma unroll
        for (int hh = 0; hh < 8; ++hh) {
            auto pr = __builtin_amdgcn_cvt_pkrtz(p[2 * hh], p[2 * hh + 1]);
            unsigned pu; __builtin_memcpy(&pu, &pr, 4);
            pk[hh] = pu;
        }
#pragma unroll
        for (int s = 0; s < 2; ++s) {       // C-frag -> B-frag(P^T): lane^32 swap
            unsigned send0 = lh ? pk[4 * s + 0] : pk[4 * s + 2];
            unsigned send1 = lh ? pk[4 * s + 1] : pk[4 * s + 3];
            unsigned r0 = (unsigned)__shfl_xor((int)send0, 32);
            unsigned r1 = (unsigned)__shfl_xor((int)send1, 32);
            H8U4 pb;
            pb.u[0] = lh ? r0 : pk[4 * s + 0];
            pb.u[1] = lh ? r1 : pk[4 * s + 1];
            pb.u[2] = lh ? pk[4 * s + 2] : r0;
            pb.u[3] = lh ? pk[4 * s + 3] : r1;
            O0 = __builtin_amdgcn_mfma_f32_32x32x16_f16(vf[s], pb.v, O0, 0, 0, 0);
            O1 = __builtin_amdgcn_mfma_f32_32x32x16_f16(vf[2 + s], pb.v, O1, 0, 0, 0);
        }
    };

    // rotated 2-deep register pipeline (no dynamic reg indexing)
    h8 kfA[4], vfA[4]; float4 hrA[4];
    h8 kfB[4], vfB[4]; float4 hrB[4];
    if (j0 < j1) {
        loadT(j0, kfA, vfA, hrA);
        int jj = j0;
        while (true) {
            if (jj + 1 < j1) loadT(jj + 1, kfB, vfB, hrB);
            comp(jj, kfA, vfA, hrA);
            if (++jj >= j1) break;
            if (jj + 1 < j1) loadT(jj + 1, kfA, vfA, hrA);
            comp(jj, kfB, vfB, hrB);
            if (++jj >= j1) break;
        }
    }

    // merge: wave1 publishes (m,l,O); wave0 flash-combines, normalizes, stores
    if (wv) {
#pragma unroll
        for (int r = 0; r < 16; ++r) { sm[lane][r] = O0[r]; sm[lane][16 + r] = O1[r]; }
        sm[lane][32] = lsum + __shfl_xor(lsum, 32);
        sm[lane][33] = mrun;
    }
    __syncthreads();
    if (!wv) {
        float l0 = lsum + __shfl_xor(lsum, 32);
        float l1 = sm[lane][32];
        float m1 = sm[lane][33];
        float m = fmaxf(mrun, m1);
        float a0 = __builtin_amdgcn_exp2f(mrun - m);
        float a1 = __builtin_amdgcn_exp2f(m1 - m);   // wave1 empty: m1=-inf -> 0
        float lt = l0 * a0 + l1 * a1;
        float inv = 1.f / lt;
        float s0 = a0 * inv, s1 = a1 * inv;
        size_t ro = fbase + (size_t)qrow * DD;
#pragma unroll
        for (int g = 0; g < 4; ++g) {
            float4 o0 = make_float4(O0[4 * g + 0] * s0 + sm[lane][4 * g + 0] * s1,
                                    O0[4 * g + 1] * s0 + sm[lane][4 * g + 1] * s1,
                                    O0[4 * g + 2] * s0 + sm[lane][4 * g + 2] * s1,
                                    O0[4 * g + 3] * s0 + sm[lane][4 * g + 3] * s1);
            *(float4*)&out[ro + 8 * g + 4 * lh] = o0;
            float4 o1 = make_float4(O1[4 * g + 0] * s0 + sm[lane][16 + 4 * g + 0] * s1,
                                    O1[4 * g + 1] * s0 + sm[lane][16 + 4 * g + 1] * s1,
                                    O1[4 * g + 2] * s0 + sm[lane][16 + 4 * g + 2] * s1,
                                    O1[4 * g + 3] * s0 + sm[lane][16 + 4 * g + 3] * s1);
            *(float4*)&out[ro + 32 + 8 * g + 4 * lh] = o1;
        }
    }
}

extern "C" void kernel_launch(void* const* d_in, const int* in_sizes, int n_in,
                              void* d_out, int out_size, void* d_ws, size_t ws_size,
                              hipStream_t stream) {
    (void)in_sizes; (void)n_in; (void)out_size; (void)ws_size;
    const float* q = (const float*)d_in[0];
    const float* k = (const float*)d_in[1];
    const float* v = (const float*)d_in[2];
    float* out = (float*)d_out;

    // ws: [hk 256KB][Ks 8MB f16][Vs 8MB f16]
    float* hk = (float*)d_ws;
    _Float16* Ks = (_Float16*)((char*)d_ws + 262144);
    _Float16* Vs = (_Float16*)((char*)d_ws + 262144 + 8388608);

    prep<<<dim3(64, 32), 64, 0, stream>>>(k, v, Ks, Vs, hk);
    rbf_attn<<<dim3(32, 64), 128, 0, stream>>>(q, Ks, Vs, hk, out);
}